// Round 12
// baseline (159.031 us; speedup 1.0000x reference)
//
#include <hip/hip_runtime.h>

// InterNet B=32,N=16,D=64,P=8. Factorized: conv(mask*[y1;y2],W_rel) =
// mask*(convA(x[o1]) + convB(x[o2])). 3 dispatches, no inter-block sync.
//   prep: x -> bf16 xt [img][px][ic]; weights -> bf16 Wt [tap][oc][ic]
//   k1:   grid 1024 = 2 blocks/image (oc half h): self/relA/relB -> xs/cA/cB
//   k2:   grid 1024 = 2 blocks/image: full combine + full aff conv (duplicated,
//         cheap) -> agg conv for oc half h -> out
// 256-thr blocks (R9-proven shape); 2x grid doubles blocks/CU for latency hiding.

#define NIMG 512
#define IMGSZ 4096

using bf16x8 = __attribute__((ext_vector_type(8))) short;
using f32x4  = __attribute__((ext_vector_type(4))) float;
using u16x8  = __attribute__((ext_vector_type(8))) unsigned short;

__device__ inline unsigned short f2bf(float f) {
  union { float f; unsigned u; } v; v.f = f;
  unsigned r = v.u + 0x7fffu + ((v.u >> 16) & 1u);
  return (unsigned short)(r >> 16);
}

// Wt slots: self [9][64][64] @0, aff @36864, rel [9][64][128] @73728,
//           agg [9][64][128] @147456.  xt: [512][64px][64ic] bf16.
__global__ __launch_bounds__(256) void prep(
    const float* __restrict__ x,
    const float* __restrict__ Wr, const float* __restrict__ Ws,
    const float* __restrict__ Wa, const float* __restrict__ Wg,
    unsigned short* __restrict__ xt, unsigned short* __restrict__ Wt)
{
  const int blk = blockIdx.x;
  if (blk < 512) {
    __shared__ __align__(16) unsigned short st[64 * 68];
    const int tid = threadIdx.x, w = tid >> 6, lane = tid & 63;
    const float* base = x + (size_t)blk * IMGSZ;
    const int px = lane;
#pragma unroll
    for (int r = 0; r < 8; ++r) {
      int ic0 = (w + 4 * r) * 2;
      const float* s = base + ic0 * 64;
      float a = s[px], c = s[64 + px];
      *(unsigned*)(st + px * 68 + ic0) = (unsigned)f2bf(a) | ((unsigned)f2bf(c) << 16);
    }
    __syncthreads();
    const int row = tid >> 2;
#pragma unroll
    for (int k = 0; k < 2; ++k) {
      int c = (tid & 3) * 2 + k;
      *(u16x8*)(xt + (size_t)blk * IMGSZ + row * 64 + c * 8) =
          *(const u16x8*)(st + row * 68 + c * 8);
    }
  } else {
    int idx = (blk - 512) * 256 + threadIdx.x;
    if (idx >= 221184) return;
    float v;
    if (idx < 73728) {
      int c = idx / 36864, r = idx % 36864;
      int t = r >> 12, oc = (r >> 6) & 63, ic = r & 63;
      v = (c == 0 ? Ws : Wa)[oc * 576 + ic * 9 + t];
    } else {
      int r2 = idx - 73728;
      int half = r2 / 73728, rr = r2 % 73728;
      int t = rr >> 13, oc = (rr >> 7) & 63, ic = rr & 127;
      v = (half ? Wg : Wr)[oc * 1152 + ic * 9 + t];
    }
    Wt[idx] = f2bf(v);
  }
}

// batch b pinned to XCD b&7 (perf heuristic; correctness never depends on it)
__device__ inline void decode_img(int j, int& b, int& o) {
  b = ((j >> 7) << 3) | (j & 7);
  o = (j >> 3) & 15;
}

__global__ __launch_bounds__(256) void k1(
    const unsigned short* __restrict__ xt,
    const unsigned short* __restrict__ Wt,
    const float* __restrict__ b_self,
    float* __restrict__ xs, float* __restrict__ cA, float* __restrict__ cB)
{
  constexpr int ROW = 72;
  __shared__ __align__(16) unsigned short sX[65 * ROW];
  const int h = blockIdx.x >> 9;            // oc half: 0 or 1
  int b, o;
  decode_img(blockIdx.x & 511, b, o);
  const int img = b * 16 + o;
  const int tid = threadIdx.x;
  const int w = tid >> 6, lane = tid & 63;

  // stage xt (bf16 [px][ic]) -> LDS; row 64 = zeros for OOB taps
  {
    const unsigned short* xo = xt + (size_t)img * IMGSZ;
    const int row = tid >> 2, c = tid & 3;
    *(u16x8*)(sX + row * ROW + c * 16)     = *(const u16x8*)(xo + row * 64 + c * 16);
    *(u16x8*)(sX + row * ROW + c * 16 + 8) = *(const u16x8*)(xo + row * 64 + c * 16 + 8);
  }
  if (tid < 36) ((unsigned*)(sX + 64 * ROW))[tid] = 0;
  __syncthreads();

  const int q = lane >> 4, n16 = lane & 15;
  const int ocb = (h * 2 + (w >> 1)) * 16;  // wave -> oc tile within half
  const int ph  = (w & 1) * 32;             // wave -> px half
  const int co = ocb + q * 4;
  const int aw64 = (ocb + n16) * 64 + q * 8;

  int pyt[2], pxt[2];
#pragma unroll
  for (int t = 0; t < 2; ++t) { int p = ph + t * 16 + n16; pyt[t] = p >> 3; pxt[t] = p & 7; }

  f32x4 aS[2] = {}, aA[2] = {}, aB[2] = {};
  const unsigned short* WS = Wt + aw64;
  const unsigned short* WA = Wt + 73728 + (ocb + n16) * 128 + q * 8;  // rel ic 0..63
  const unsigned short* WB = WA + 64;                                 // rel ic 64..127
#pragma unroll
  for (int tap = 0; tap < 9; ++tap) {
    const int dy = tap / 3 - 1, dx = tap % 3 - 1;
    int spt[2];
#pragma unroll
    for (int t = 0; t < 2; ++t) {
      int sy = pyt[t] + dy, sx = pxt[t] + dx;
      spt[t] = ((unsigned)sy < 8u && (unsigned)sx < 8u) ? (sy * 8 + sx) : 64;
    }
#pragma unroll
    for (int ks = 0; ks < 2; ++ks) {
      bf16x8 as = *(const bf16x8*)(WS + tap * 4096 + ks * 32);
      bf16x8 aa = *(const bf16x8*)(WA + tap * 8192 + ks * 32);
      bf16x8 ab = *(const bf16x8*)(WB + tap * 8192 + ks * 32);
#pragma unroll
      for (int t = 0; t < 2; ++t) {
        bf16x8 bt = *(const bf16x8*)(sX + spt[t] * ROW + ks * 32 + q * 8);
        aS[t] = __builtin_amdgcn_mfma_f32_16x16x32_bf16(as, bt, aS[t], 0, 0, 0);
        aA[t] = __builtin_amdgcn_mfma_f32_16x16x32_bf16(aa, bt, aA[t], 0, 0, 0);
        aB[t] = __builtin_amdgcn_mfma_f32_16x16x32_bf16(ab, bt, aB[t], 0, 0, 0);
      }
    }
  }

  const size_t ib = (size_t)img * IMGSZ;
#pragma unroll
  for (int t = 0; t < 2; ++t) {
    int p = ph + t * 16 + n16;
    f32x4 vs = aS[t];
#pragma unroll
    for (int r = 0; r < 4; ++r) vs[r] = fmaxf(vs[r] + b_self[co + r], 0.f);
    *(f32x4*)(xs + ib + p * 64 + co) = vs;
    *(f32x4*)(cA + ib + p * 64 + co) = aA[t];
    *(f32x4*)(cB + ib + p * 64 + co) = aB[t];
  }
}

__global__ __launch_bounds__(256) void k2(
    const unsigned short* __restrict__ xt,
    const int* __restrict__ g_idx,
    const unsigned short* __restrict__ Wt,
    const float* __restrict__ b_rel, const float* __restrict__ b_aff,
    const float* __restrict__ b_agg,
    const float* __restrict__ xs, const float* __restrict__ cA,
    const float* __restrict__ cB,
    float* __restrict__ out)
{
  constexpr int ROW = 72, ROW2 = 136;
  __shared__ __align__(16) unsigned short sX[65 * ROW2];   // [a | x] bf16
  __shared__ __align__(16) unsigned short sPred[65 * ROW]; // pred bf16
  __shared__ int so1c[16], so2c[16];
  __shared__ int scnt;

  const int h = blockIdx.x >> 9;            // agg oc half: 0 or 1
  int b, i;
  decode_img(blockIdx.x & 511, b, i);
  const int img = b * 16 + i;
  const int tid = threadIdx.x;
  const int w = tid >> 6, lane = tid & 63;

  // mask compaction (wave 0)
  if (tid < 64) {
    int v1 = 0, v2 = 0, m = 0;
    if (tid < 15) {
      const int* gp = g_idx + ((size_t)b * 240 + i * 15 + tid) * 3;
      v1 = gp[0] & 15;   // tile(x, n-1): x1[j] = x[j % 16]
      v2 = gp[1] & 15;
      m  = gp[2];
    }
    unsigned long long bal = __ballot(m != 0);
    if (m) {
      int pos = __popcll(bal & ((1ull << tid) - 1ull));
      so1c[pos] = v1; so2c[pos] = v2;
    }
    if (tid == 0) scnt = (int)__popcll(bal);
  }

  // stage own x (bf16 [px][ic]) -> sX cols 64..127
  {
    const unsigned short* xo = xt + (size_t)img * IMGSZ;
    const int row = tid >> 2, c = tid & 3;
    *(u16x8*)(sX + row * ROW2 + 64 + c * 16)     = *(const u16x8*)(xo + row * 64 + c * 16);
    *(u16x8*)(sX + row * ROW2 + 64 + c * 16 + 8) = *(const u16x8*)(xo + row * 64 + c * 16 + 8);
  }
  if (tid < 68) ((unsigned*)(sX + 64 * ROW2))[tid] = 0;
  if (tid < 36) ((unsigned*)(sPred + 64 * ROW))[tid] = 0;
  __syncthreads();

  // ---- combine (full, duplicated across the 2 blocks of this image):
  //      pred = xs + cnt0*relu(br) + sum_{m=1} relu(cA[o1]+cB[o2]+br)
  {
    const int e0 = tid * 16;            // 16 consecutive [px][ic] elements
    const int e_px = tid >> 2, e_ic = (tid & 3) * 16;
    const size_t bb = (size_t)b * 16 * IMGSZ;
    const int cnt1 = scnt, cnt0 = 15 - cnt1;
    float acc[16], br[16];
    const f32x4* xp = (const f32x4*)(xs + (size_t)img * IMGSZ + e0);
#pragma unroll
    for (int u4 = 0; u4 < 4; ++u4) {
      f32x4 v = xp[u4];
#pragma unroll
      for (int r = 0; r < 4; ++r) {
        int u = u4 * 4 + r;
        br[u] = b_rel[e_ic + u];
        acc[u] = v[r] + (float)cnt0 * fmaxf(br[u], 0.f);
      }
    }
    for (int j = 0; j < cnt1; ++j) {
      const f32x4* a1 = (const f32x4*)(cA + bb + (size_t)so1c[j] * IMGSZ + e0);
      const f32x4* a2 = (const f32x4*)(cB + bb + (size_t)so2c[j] * IMGSZ + e0);
#pragma unroll
      for (int u4 = 0; u4 < 4; ++u4) {
        f32x4 v1 = a1[u4], v2 = a2[u4];
#pragma unroll
        for (int r = 0; r < 4; ++r)
          acc[u4 * 4 + r] += fmaxf(v1[r] + v2[r] + br[u4 * 4 + r], 0.f);
      }
    }
    u16x8 p0, p1;
#pragma unroll
    for (int u = 0; u < 8; ++u) { p0[u] = f2bf(acc[u]); p1[u] = f2bf(acc[8 + u]); }
    *(u16x8*)(sPred + e_px * ROW + e_ic)     = p0;
    *(u16x8*)(sPred + e_px * ROW + e_ic + 8) = p1;
  }
  __syncthreads();

  const int q = lane >> 4, n16 = lane & 15;

  // ---- aff conv (full, duplicated): sPred -> a -> sX cols 0..63
  {
    const int ocb = w * 16;
    const int co = ocb + q * 4;
    const int aw64 = (ocb + n16) * 64 + q * 8;
    int pyt[4], pxt[4];
#pragma unroll
    for (int t = 0; t < 4; ++t) { int p = t * 16 + n16; pyt[t] = p >> 3; pxt[t] = p & 7; }
    f32x4 f[4] = {};
    const unsigned short* WA = Wt + 36864 + aw64;
#pragma unroll
    for (int tap = 0; tap < 9; ++tap) {
      const int dy = tap / 3 - 1, dx = tap % 3 - 1;
      int spt[4];
#pragma unroll
      for (int t = 0; t < 4; ++t) {
        int sy = pyt[t] + dy, sx = pxt[t] + dx;
        spt[t] = ((unsigned)sy < 8u && (unsigned)sx < 8u) ? (sy * 8 + sx) : 64;
      }
#pragma unroll
      for (int ks = 0; ks < 2; ++ks) {
        bf16x8 a = *(const bf16x8*)(WA + tap * 4096 + ks * 32);
#pragma unroll
        for (int t = 0; t < 4; ++t) {
          bf16x8 bt = *(const bf16x8*)(sPred + spt[t] * ROW + ks * 32 + q * 8);
          f[t] = __builtin_amdgcn_mfma_f32_16x16x32_bf16(a, bt, f[t], 0, 0, 0);
        }
      }
    }
#pragma unroll
    for (int t = 0; t < 4; ++t) {
      int p = t * 16 + n16;
      float v0 = fmaxf(f[t][0] + b_aff[co + 0], 0.f);
      float v1 = fmaxf(f[t][1] + b_aff[co + 1], 0.f);
      float v2 = fmaxf(f[t][2] + b_aff[co + 2], 0.f);
      float v3 = fmaxf(f[t][3] + b_aff[co + 3], 0.f);
      uint2 pk;
      pk.x = (unsigned)f2bf(v0) | ((unsigned)f2bf(v1) << 16);
      pk.y = (unsigned)f2bf(v2) | ((unsigned)f2bf(v3) << 16);
      *(uint2*)(sX + p * ROW2 + co) = pk;
    }
  }
  __syncthreads();

  // ---- agg conv (oc half h): sX (128 ic: [a|x]) -> out fp32 [ic][px]
  {
    const int ocb = (h * 2 + (w >> 1)) * 16;
    const int ph  = (w & 1) * 32;
    const int co = ocb + q * 4;
    const int aw128 = (ocb + n16) * 128 + q * 8;
    int pyt[2], pxt[2];
#pragma unroll
    for (int t = 0; t < 2; ++t) { int p = ph + t * 16 + n16; pyt[t] = p >> 3; pxt[t] = p & 7; }
    f32x4 g[2] = {};
    const unsigned short* WG = Wt + 147456 + aw128;
#pragma unroll
    for (int tap = 0; tap < 9; ++tap) {
      const int dy = tap / 3 - 1, dx = tap % 3 - 1;
      int spt[2];
#pragma unroll
      for (int t = 0; t < 2; ++t) {
        int sy = pyt[t] + dy, sx = pxt[t] + dx;
        spt[t] = ((unsigned)sy < 8u && (unsigned)sx < 8u) ? (sy * 8 + sx) : 64;
      }
#pragma unroll
      for (int ks = 0; ks < 4; ++ks) {
        bf16x8 a = *(const bf16x8*)(WG + tap * 8192 + ks * 32);
#pragma unroll
        for (int t = 0; t < 2; ++t) {
          bf16x8 bt = *(const bf16x8*)(sX + spt[t] * ROW2 + ks * 32 + q * 8);
          g[t] = __builtin_amdgcn_mfma_f32_16x16x32_bf16(a, bt, g[t], 0, 0, 0);
        }
      }
    }
    float* ob = out + (size_t)img * IMGSZ;
#pragma unroll
    for (int t = 0; t < 2; ++t) {
      int p = ph + t * 16 + n16;
#pragma unroll
      for (int r = 0; r < 4; ++r)
        ob[(co + r) * 64 + p] = fmaxf(g[t][r] + b_agg[co + r], 0.f);
    }
  }
}

extern "C" void kernel_launch(void* const* d_in, const int* in_sizes, int n_in,
                              void* d_out, int out_size, void* d_ws, size_t ws_size,
                              hipStream_t stream) {
  const float* x      = (const float*)d_in[0];
  const int*   g_idx  = (const int*)  d_in[1];
  const float* W_rel  = (const float*)d_in[2];
  const float* b_rel  = (const float*)d_in[3];
  const float* W_self = (const float*)d_in[4];
  const float* b_self = (const float*)d_in[5];
  const float* W_aff  = (const float*)d_in[6];
  const float* b_aff  = (const float*)d_in[7];
  const float* W_agg  = (const float*)d_in[8];
  const float* b_agg  = (const float*)d_in[9];
  float* out = (float*)d_out;

  float* ws = (float*)d_ws;
  float* xs = ws;                                            // [512][64][64] fp32
  float* cA = ws + 2097152;
  float* cB = ws + 2 * 2097152;
  unsigned short* xt = (unsigned short*)(ws + 3 * 2097152);  // [512][64][64] bf16
  unsigned short* Wt = xt + 2097152;                         // 221184 bf16

  prep<<<512 + 864, 256, 0, stream>>>(x, W_rel, W_self, W_aff, W_agg, xt, Wt);
  k1<<<2 * NIMG, 256, 0, stream>>>(xt, Wt, b_self, xs, cA, cB);
  k2<<<2 * NIMG, 256, 0, stream>>>(xt, g_idx, Wt, b_rel, b_aff, b_agg,
                                   xs, cA, cB, out);
}

// Round 13
// 124.461 us; speedup vs baseline: 1.2778x; 1.2778x over previous
//
#include <hip/hip_runtime.h>

// InterNet B=32,N=16,D=64,P=8. Factorized: conv(mask*[y1;y2],W_rel) =
// mask*(convA(x[o1]) + convB(x[o2])). 3 dispatches, no inter-block sync.
//   prep: x -> bf16 xt [img][px][ic]; weights -> bf16 Wt [tap][oc][ic]
//   k1:   per image: self/relA/relB convs -> xs/cA/cB fp32 [px][ic]
//   k2:   per image: combine (15 static pairs, 30-load bursts for MLP) ->
//         pred(LDS) -> aff conv -> a(LDS[a|x]) -> agg conv(128ic) -> out
// R12 lesson: combine was latency-serialized at VGPR=48; this version forces
// all 30 gather loads in flight per pass (launch_bounds(256,2) -> VGPR room).

#define NIMG 512
#define IMGSZ 4096

using bf16x8 = __attribute__((ext_vector_type(8))) short;
using f32x4  = __attribute__((ext_vector_type(4))) float;
using u16x8  = __attribute__((ext_vector_type(8))) unsigned short;

__device__ inline unsigned short f2bf(float f) {
  union { float f; unsigned u; } v; v.f = f;
  unsigned r = v.u + 0x7fffu + ((v.u >> 16) & 1u);
  return (unsigned short)(r >> 16);
}

// Wt slots: self [9][64][64] @0, aff @36864, rel [9][64][128] @73728,
//           agg [9][64][128] @147456.  xt: [512][64px][64ic] bf16.
__global__ __launch_bounds__(256) void prep(
    const float* __restrict__ x,
    const float* __restrict__ Wr, const float* __restrict__ Ws,
    const float* __restrict__ Wa, const float* __restrict__ Wg,
    unsigned short* __restrict__ xt, unsigned short* __restrict__ Wt)
{
  const int blk = blockIdx.x;
  if (blk < 512) {
    __shared__ __align__(16) unsigned short st[64 * 68];
    const int tid = threadIdx.x, w = tid >> 6, lane = tid & 63;
    const float* base = x + (size_t)blk * IMGSZ;
    const int px = lane;
#pragma unroll
    for (int r = 0; r < 8; ++r) {
      int ic0 = (w + 4 * r) * 2;
      const float* s = base + ic0 * 64;
      float a = s[px], c = s[64 + px];
      *(unsigned*)(st + px * 68 + ic0) = (unsigned)f2bf(a) | ((unsigned)f2bf(c) << 16);
    }
    __syncthreads();
    const int row = tid >> 2;
#pragma unroll
    for (int k = 0; k < 2; ++k) {
      int c = (tid & 3) * 2 + k;
      *(u16x8*)(xt + (size_t)blk * IMGSZ + row * 64 + c * 8) =
          *(const u16x8*)(st + row * 68 + c * 8);
    }
  } else {
    int idx = (blk - 512) * 256 + threadIdx.x;
    if (idx >= 221184) return;
    float v;
    if (idx < 73728) {
      int c = idx / 36864, r = idx % 36864;
      int t = r >> 12, oc = (r >> 6) & 63, ic = r & 63;
      v = (c == 0 ? Ws : Wa)[oc * 576 + ic * 9 + t];
    } else {
      int r2 = idx - 73728;
      int half = r2 / 73728, rr = r2 % 73728;
      int t = rr >> 13, oc = (rr >> 7) & 63, ic = rr & 127;
      v = (half ? Wg : Wr)[oc * 1152 + ic * 9 + t];
    }
    Wt[idx] = f2bf(v);
  }
}

// batch b pinned to XCD b&7 (perf heuristic; correctness never depends on it)
__device__ inline void decode_img(int j, int& b, int& o) {
  b = ((j >> 7) << 3) | (j & 7);
  o = (j >> 3) & 15;
}

__global__ __launch_bounds__(256) void k1(
    const unsigned short* __restrict__ xt,
    const unsigned short* __restrict__ Wt,
    const float* __restrict__ b_self,
    float* __restrict__ xs, float* __restrict__ cA, float* __restrict__ cB)
{
  constexpr int ROW = 72;
  __shared__ __align__(16) unsigned short sX[65 * ROW];
  int b, o;
  decode_img(blockIdx.x, b, o);
  const int img = b * 16 + o;
  const int tid = threadIdx.x;
  const int w = tid >> 6, lane = tid & 63;

  // stage xt (bf16 [px][ic]) -> LDS; row 64 = zeros for OOB taps
  {
    const unsigned short* xo = xt + (size_t)img * IMGSZ;
    const int row = tid >> 2, c = tid & 3;
    *(u16x8*)(sX + row * ROW + c * 16)     = *(const u16x8*)(xo + row * 64 + c * 16);
    *(u16x8*)(sX + row * ROW + c * 16 + 8) = *(const u16x8*)(xo + row * 64 + c * 16 + 8);
  }
  if (tid < 36) ((unsigned*)(sX + 64 * ROW))[tid] = 0;
  __syncthreads();

  const int q = lane >> 4, n16 = lane & 15;
  const int ocb = w * 16;
  const int co = ocb + q * 4;
  const int aw64 = (ocb + n16) * 64 + q * 8;

  int pyt[4], pxt[4];
#pragma unroll
  for (int t = 0; t < 4; ++t) { int p = t * 16 + n16; pyt[t] = p >> 3; pxt[t] = p & 7; }

  f32x4 aS[4] = {}, aA[4] = {}, aB[4] = {};
  const unsigned short* WS = Wt + aw64;
  const unsigned short* WA = Wt + 73728 + (ocb + n16) * 128 + q * 8;  // rel ic 0..63
  const unsigned short* WB = WA + 64;                                 // rel ic 64..127
#pragma unroll
  for (int tap = 0; tap < 9; ++tap) {
    const int dy = tap / 3 - 1, dx = tap % 3 - 1;
    int spt[4];
#pragma unroll
    for (int t = 0; t < 4; ++t) {
      int sy = pyt[t] + dy, sx = pxt[t] + dx;
      spt[t] = ((unsigned)sy < 8u && (unsigned)sx < 8u) ? (sy * 8 + sx) : 64;
    }
#pragma unroll
    for (int ks = 0; ks < 2; ++ks) {
      bf16x8 as = *(const bf16x8*)(WS + tap * 4096 + ks * 32);
      bf16x8 aa = *(const bf16x8*)(WA + tap * 8192 + ks * 32);
      bf16x8 ab = *(const bf16x8*)(WB + tap * 8192 + ks * 32);
#pragma unroll
      for (int t = 0; t < 4; ++t) {
        bf16x8 bt = *(const bf16x8*)(sX + spt[t] * ROW + ks * 32 + q * 8);
        aS[t] = __builtin_amdgcn_mfma_f32_16x16x32_bf16(as, bt, aS[t], 0, 0, 0);
        aA[t] = __builtin_amdgcn_mfma_f32_16x16x32_bf16(aa, bt, aA[t], 0, 0, 0);
        aB[t] = __builtin_amdgcn_mfma_f32_16x16x32_bf16(ab, bt, aB[t], 0, 0, 0);
      }
    }
  }

  const size_t ib = (size_t)img * IMGSZ;
#pragma unroll
  for (int t = 0; t < 4; ++t) {
    int p = t * 16 + n16;
    f32x4 vs = aS[t];
#pragma unroll
    for (int r = 0; r < 4; ++r) vs[r] = fmaxf(vs[r] + b_self[co + r], 0.f);
    *(f32x4*)(xs + ib + p * 64 + co) = vs;
    *(f32x4*)(cA + ib + p * 64 + co) = aA[t];
    *(f32x4*)(cB + ib + p * 64 + co) = aB[t];
  }
}

__global__ __launch_bounds__(256, 2) void k2(
    const unsigned short* __restrict__ xt,
    const int* __restrict__ g_idx,
    const unsigned short* __restrict__ Wt,
    const float* __restrict__ b_rel, const float* __restrict__ b_aff,
    const float* __restrict__ b_agg,
    const float* __restrict__ xs, const float* __restrict__ cA,
    const float* __restrict__ cB,
    float* __restrict__ out)
{
  constexpr int ROW = 72, ROW2 = 136;
  __shared__ __align__(16) unsigned short sX[65 * ROW2];   // [a | x] bf16
  __shared__ __align__(16) unsigned short sPred[65 * ROW]; // pred bf16
  __shared__ int so1[15], so2[15];
  __shared__ float sm[15];

  int b, i;
  decode_img(blockIdx.x, b, i);
  const int img = b * 16 + i;
  const int tid = threadIdx.x;
  const int w = tid >> 6, lane = tid & 63;

  // stage pair table (all 15 pairs; m in {0,1} as float multiplier)
  if (tid < 15) {
    const int* gp = g_idx + ((size_t)b * 240 + i * 15 + tid) * 3;
    so1[tid] = gp[0] & 15;   // tile(x, n-1): x1[j] = x[j % 16]
    so2[tid] = gp[1] & 15;
    sm[tid]  = (float)gp[2];
  }

  // stage own x (bf16 [px][ic]) -> sX cols 64..127
  {
    const unsigned short* xo = xt + (size_t)img * IMGSZ;
    const int row = tid >> 2, c = tid & 3;
    *(u16x8*)(sX + row * ROW2 + 64 + c * 16)     = *(const u16x8*)(xo + row * 64 + c * 16);
    *(u16x8*)(sX + row * ROW2 + 64 + c * 16 + 8) = *(const u16x8*)(xo + row * 64 + c * 16 + 8);
  }
  if (tid < 68) ((unsigned*)(sX + 64 * ROW2))[tid] = 0;
  if (tid < 36) ((unsigned*)(sPred + 64 * ROW))[tid] = 0;
  __syncthreads();

  // ---- combine: pred = xs + sum_j relu(m_j*(cA[o1_j]+cB[o2_j]) + br)
  // 4 passes x 4 floats/thread; each pass issues all 30 gather loads before
  // consuming (memory-level parallelism -- the R12 fix).
  {
    const size_t bb = (size_t)b * 16 * IMGSZ;
    const float* xbase = xs + (size_t)img * IMGSZ;
#pragma unroll 1
    for (int pass = 0; pass < 4; ++pass) {
      const int e = tid * 4 + pass * 1024;   // 4 consecutive [px][ic] floats
      const int e_px = e >> 6, e_ic = e & 63;
      f32x4 v1[15], v2[15];
#pragma unroll
      for (int j = 0; j < 15; ++j) {
        v1[j] = *(const f32x4*)(cA + bb + (size_t)so1[j] * IMGSZ + e);
        v2[j] = *(const f32x4*)(cB + bb + (size_t)so2[j] * IMGSZ + e);
      }
      f32x4 xv = *(const f32x4*)(xbase + e);
      float acc[4], br[4];
#pragma unroll
      for (int r = 0; r < 4; ++r) { br[r] = b_rel[e_ic + r]; acc[r] = xv[r]; }
#pragma unroll
      for (int j = 0; j < 15; ++j) {
        float m = sm[j];
#pragma unroll
        for (int r = 0; r < 4; ++r)
          acc[r] += fmaxf(m * (v1[j][r] + v2[j][r]) + br[r], 0.f);
      }
      uint2 pk;
      pk.x = (unsigned)f2bf(acc[0]) | ((unsigned)f2bf(acc[1]) << 16);
      pk.y = (unsigned)f2bf(acc[2]) | ((unsigned)f2bf(acc[3]) << 16);
      *(uint2*)(sPred + e_px * ROW + e_ic) = pk;
    }
  }
  __syncthreads();

  const int q = lane >> 4, n16 = lane & 15;
  const int ocb = w * 16;
  const int co = ocb + q * 4;
  const int aw64  = (ocb + n16) * 64 + q * 8;
  const int aw128 = (ocb + n16) * 128 + q * 8;

  int pyt[4], pxt[4];
#pragma unroll
  for (int t = 0; t < 4; ++t) { int p = t * 16 + n16; pyt[t] = p >> 3; pxt[t] = p & 7; }

  // ---- aff conv: sPred -> a -> sX cols 0..63
  {
    f32x4 f[4] = {};
    const unsigned short* WA = Wt + 36864 + aw64;
#pragma unroll
    for (int tap = 0; tap < 9; ++tap) {
      const int dy = tap / 3 - 1, dx = tap % 3 - 1;
      int spt[4];
#pragma unroll
      for (int t = 0; t < 4; ++t) {
        int sy = pyt[t] + dy, sx = pxt[t] + dx;
        spt[t] = ((unsigned)sy < 8u && (unsigned)sx < 8u) ? (sy * 8 + sx) : 64;
      }
#pragma unroll
      for (int ks = 0; ks < 2; ++ks) {
        bf16x8 a = *(const bf16x8*)(WA + tap * 4096 + ks * 32);
#pragma unroll
        for (int t = 0; t < 4; ++t) {
          bf16x8 bt = *(const bf16x8*)(sPred + spt[t] * ROW + ks * 32 + q * 8);
          f[t] = __builtin_amdgcn_mfma_f32_16x16x32_bf16(a, bt, f[t], 0, 0, 0);
        }
      }
    }
#pragma unroll
    for (int t = 0; t < 4; ++t) {
      int p = t * 16 + n16;
      float v0 = fmaxf(f[t][0] + b_aff[co + 0], 0.f);
      float v1 = fmaxf(f[t][1] + b_aff[co + 1], 0.f);
      float v2 = fmaxf(f[t][2] + b_aff[co + 2], 0.f);
      float v3 = fmaxf(f[t][3] + b_aff[co + 3], 0.f);
      uint2 pk;
      pk.x = (unsigned)f2bf(v0) | ((unsigned)f2bf(v1) << 16);
      pk.y = (unsigned)f2bf(v2) | ((unsigned)f2bf(v3) << 16);
      *(uint2*)(sX + p * ROW2 + co) = pk;
    }
  }
  __syncthreads();

  // ---- agg conv: sX (128 ic: [a|x]) -> out fp32 [ic][px]
  {
    f32x4 g[4] = {};
    const unsigned short* WG = Wt + 147456 + aw128;
#pragma unroll
    for (int tap = 0; tap < 9; ++tap) {
      const int dy = tap / 3 - 1, dx = tap % 3 - 1;
      int spt[4];
#pragma unroll
      for (int t = 0; t < 4; ++t) {
        int sy = pyt[t] + dy, sx = pxt[t] + dx;
        spt[t] = ((unsigned)sy < 8u && (unsigned)sx < 8u) ? (sy * 8 + sx) : 64;
      }
#pragma unroll
      for (int ks = 0; ks < 4; ++ks) {
        bf16x8 a = *(const bf16x8*)(WG + tap * 8192 + ks * 32);
#pragma unroll
        for (int t = 0; t < 4; ++t) {
          bf16x8 bt = *(const bf16x8*)(sX + spt[t] * ROW2 + ks * 32 + q * 8);
          g[t] = __builtin_amdgcn_mfma_f32_16x16x32_bf16(a, bt, g[t], 0, 0, 0);
        }
      }
    }
    float* ob = out + (size_t)img * IMGSZ;
#pragma unroll
    for (int t = 0; t < 4; ++t) {
      int p = t * 16 + n16;
#pragma unroll
      for (int r = 0; r < 4; ++r)
        ob[(co + r) * 64 + p] = fmaxf(g[t][r] + b_agg[co + r], 0.f);
    }
  }
}

extern "C" void kernel_launch(void* const* d_in, const int* in_sizes, int n_in,
                              void* d_out, int out_size, void* d_ws, size_t ws_size,
                              hipStream_t stream) {
  const float* x      = (const float*)d_in[0];
  const int*   g_idx  = (const int*)  d_in[1];
  const float* W_rel  = (const float*)d_in[2];
  const float* b_rel  = (const float*)d_in[3];
  const float* W_self = (const float*)d_in[4];
  const float* b_self = (const float*)d_in[5];
  const float* W_aff  = (const float*)d_in[6];
  const float* b_aff  = (const float*)d_in[7];
  const float* W_agg  = (const float*)d_in[8];
  const float* b_agg  = (const float*)d_in[9];
  float* out = (float*)d_out;

  float* ws = (float*)d_ws;
  float* xs = ws;                                            // [512][64][64] fp32
  float* cA = ws + 2097152;
  float* cB = ws + 2 * 2097152;
  unsigned short* xt = (unsigned short*)(ws + 3 * 2097152);  // [512][64][64] bf16
  unsigned short* Wt = xt + 2097152;                         // 221184 bf16

  prep<<<512 + 864, 256, 0, stream>>>(x, W_rel, W_self, W_aff, W_agg, xt, Wt);
  k1<<<NIMG, 256, 0, stream>>>(xt, Wt, b_self, xs, cA, cB);
  k2<<<NIMG, 256, 0, stream>>>(xt, g_idx, Wt, b_rel, b_aff, b_agg,
                               xs, cA, cB, out);
}

// Round 14
// 122.571 us; speedup vs baseline: 1.2975x; 1.0154x over previous
//
#include <hip/hip_runtime.h>

// InterNet B=32,N=16,D=64,P=8. Factorized: conv(mask*[y1;y2],W_rel) =
// mask*(convA(x[o1]) + convB(x[o2])). 3 dispatches, no inter-block sync.
//   prep_w: weights -> bf16 Wt [tap][oc][ic]  (tiny)
//   k1: per image: stage x fp32 -> LDS bf16; relA/relB convs -> cA/cB fp32
//   k2: per image: stage x -> LDS; self conv -> xs (LDS, fp32);
//       burst combine (15 static pairs, 30 loads in flight) -> pred(LDS) ->
//       aff conv -> a(LDS[a|x]) -> agg conv(128ic) -> out
// vs R13: xt and xs tensors eliminated (self conv recomputed in k2 from the
// already-staged x; bitwise-identical inputs -> identical xs values).

#define NIMG 512
#define IMGSZ 4096

using bf16x8 = __attribute__((ext_vector_type(8))) short;
using f32x4  = __attribute__((ext_vector_type(4))) float;
using u16x8  = __attribute__((ext_vector_type(8))) unsigned short;

__device__ inline unsigned short f2bf(float f) {
  union { float f; unsigned u; } v; v.f = f;
  unsigned r = v.u + 0x7fffu + ((v.u >> 16) & 1u);
  return (unsigned short)(r >> 16);
}

// Wt slots: self [9][64][64] @0, aff @36864, rel [9][64][128] @73728,
//           agg [9][64][128] @147456.
__global__ __launch_bounds__(256) void prep_w(
    const float* __restrict__ Wr, const float* __restrict__ Ws,
    const float* __restrict__ Wa, const float* __restrict__ Wg,
    unsigned short* __restrict__ Wt)
{
  int idx = blockIdx.x * 256 + threadIdx.x;
  if (idx >= 221184) return;
  float v;
  if (idx < 73728) {
    int c = idx / 36864, r = idx % 36864;
    int t = r >> 12, oc = (r >> 6) & 63, ic = r & 63;
    v = (c == 0 ? Ws : Wa)[oc * 576 + ic * 9 + t];
  } else {
    int r2 = idx - 73728;
    int half = r2 / 73728, rr = r2 % 73728;
    int t = rr >> 13, oc = (rr >> 7) & 63, ic = rr & 127;
    v = (half ? Wg : Wr)[oc * 1152 + ic * 9 + t];
  }
  Wt[idx] = f2bf(v);
}

// batch b pinned to XCD b&7 (perf heuristic; correctness never depends on it)
__device__ inline void decode_img(int j, int& b, int& o) {
  b = ((j >> 7) << 3) | (j & 7);
  o = (j >> 3) & 15;
}

// stage x (fp32 [ic][px]) -> LDS bf16 [px][stride ROWX], cols at +coff.
// 256 threads; w = tid>>6 (4 waves), lane px.
template<int ROWX>
__device__ inline void stage_x(const float* __restrict__ xb,
                               unsigned short* __restrict__ s,
                               int coff, int w, int px) {
#pragma unroll
  for (int r = 0; r < 8; ++r) {
    int ic0 = (w + 4 * r) * 2;
    const float* sp = xb + ic0 * 64;
    float a = sp[px], c = sp[64 + px];
    *(unsigned*)(s + px * ROWX + coff + ic0) =
        (unsigned)f2bf(a) | ((unsigned)f2bf(c) << 16);
  }
}

__global__ __launch_bounds__(256) void k1(
    const float* __restrict__ x,
    const unsigned short* __restrict__ Wt,
    float* __restrict__ cA, float* __restrict__ cB)
{
  constexpr int ROW = 72;
  __shared__ __align__(16) unsigned short sX[65 * ROW];
  int b, o;
  decode_img(blockIdx.x, b, o);
  const int img = b * 16 + o;
  const int tid = threadIdx.x;
  const int w = tid >> 6, lane = tid & 63;

  stage_x<ROW>(x + (size_t)img * IMGSZ, sX, 0, w, lane);
  if (tid < 36) ((unsigned*)(sX + 64 * ROW))[tid] = 0;
  __syncthreads();

  const int q = lane >> 4, n16 = lane & 15;
  const int ocb = w * 16;
  const int co = ocb + q * 4;

  int pyt[4], pxt[4];
#pragma unroll
  for (int t = 0; t < 4; ++t) { int p = t * 16 + n16; pyt[t] = p >> 3; pxt[t] = p & 7; }

  f32x4 aA[4] = {}, aB[4] = {};
  const unsigned short* WA = Wt + 73728 + (ocb + n16) * 128 + q * 8;  // rel ic 0..63
  const unsigned short* WB = WA + 64;                                 // rel ic 64..127
#pragma unroll
  for (int tap = 0; tap < 9; ++tap) {
    const int dy = tap / 3 - 1, dx = tap % 3 - 1;
    int spt[4];
#pragma unroll
    for (int t = 0; t < 4; ++t) {
      int sy = pyt[t] + dy, sx = pxt[t] + dx;
      spt[t] = ((unsigned)sy < 8u && (unsigned)sx < 8u) ? (sy * 8 + sx) : 64;
    }
#pragma unroll
    for (int ks = 0; ks < 2; ++ks) {
      bf16x8 aa = *(const bf16x8*)(WA + tap * 8192 + ks * 32);
      bf16x8 ab = *(const bf16x8*)(WB + tap * 8192 + ks * 32);
#pragma unroll
      for (int t = 0; t < 4; ++t) {
        bf16x8 bt = *(const bf16x8*)(sX + spt[t] * ROW + ks * 32 + q * 8);
        aA[t] = __builtin_amdgcn_mfma_f32_16x16x32_bf16(aa, bt, aA[t], 0, 0, 0);
        aB[t] = __builtin_amdgcn_mfma_f32_16x16x32_bf16(ab, bt, aB[t], 0, 0, 0);
      }
    }
  }

  const size_t ib = (size_t)img * IMGSZ;
#pragma unroll
  for (int t = 0; t < 4; ++t) {
    int p = t * 16 + n16;
    *(f32x4*)(cA + ib + p * 64 + co) = aA[t];
    *(f32x4*)(cB + ib + p * 64 + co) = aB[t];
  }
}

__global__ __launch_bounds__(256, 2) void k2(
    const float* __restrict__ x,
    const int* __restrict__ g_idx,
    const unsigned short* __restrict__ Wt,
    const float* __restrict__ b_rel, const float* __restrict__ b_self,
    const float* __restrict__ b_aff, const float* __restrict__ b_agg,
    const float* __restrict__ cA, const float* __restrict__ cB,
    float* __restrict__ out)
{
  constexpr int ROW = 72, ROW2 = 136, XROW = 68;
  __shared__ __align__(16) unsigned short sX[65 * ROW2];   // [a | x] bf16
  __shared__ __align__(16) unsigned short sPred[65 * ROW]; // pred bf16
  __shared__ __align__(16) float sXS[64 * XROW];           // xs fp32
  __shared__ int so1[15], so2[15];
  __shared__ float sm[15];

  int b, i;
  decode_img(blockIdx.x, b, i);
  const int img = b * 16 + i;
  const int tid = threadIdx.x;
  const int w = tid >> 6, lane = tid & 63;

  if (tid < 15) {
    const int* gp = g_idx + ((size_t)b * 240 + i * 15 + tid) * 3;
    so1[tid] = gp[0] & 15;   // tile(x, n-1): x1[j] = x[j % 16]
    so2[tid] = gp[1] & 15;
    sm[tid]  = (float)gp[2];
  }

  stage_x<ROW2>(x + (size_t)img * IMGSZ, sX, 64, w, lane);
  if (tid < 68) ((unsigned*)(sX + 64 * ROW2))[tid] = 0;
  if (tid < 36) ((unsigned*)(sPred + 64 * ROW))[tid] = 0;
  __syncthreads();

  const int q = lane >> 4, n16 = lane & 15;
  const int ocb = w * 16;
  const int co = ocb + q * 4;
  const int aw64  = (ocb + n16) * 64 + q * 8;
  const int aw128 = (ocb + n16) * 128 + q * 8;

  int pyt[4], pxt[4];
#pragma unroll
  for (int t = 0; t < 4; ++t) { int p = t * 16 + n16; pyt[t] = p >> 3; pxt[t] = p & 7; }

  // ---- self conv (from staged x) -> xs in LDS fp32 (bitwise = old k1 xs)
  {
    f32x4 f[4] = {};
    const unsigned short* WS = Wt + aw64;
#pragma unroll
    for (int tap = 0; tap < 9; ++tap) {
      const int dy = tap / 3 - 1, dx = tap % 3 - 1;
      int spt[4];
#pragma unroll
      for (int t = 0; t < 4; ++t) {
        int sy = pyt[t] + dy, sx = pxt[t] + dx;
        spt[t] = ((unsigned)sy < 8u && (unsigned)sx < 8u) ? (sy * 8 + sx) : 64;
      }
#pragma unroll
      for (int ks = 0; ks < 2; ++ks) {
        bf16x8 a = *(const bf16x8*)(WS + tap * 4096 + ks * 32);
#pragma unroll
        for (int t = 0; t < 4; ++t) {
          bf16x8 bt = *(const bf16x8*)(sX + spt[t] * ROW2 + 64 + ks * 32 + q * 8);
          f[t] = __builtin_amdgcn_mfma_f32_16x16x32_bf16(a, bt, f[t], 0, 0, 0);
        }
      }
    }
#pragma unroll
    for (int t = 0; t < 4; ++t) {
      int p = t * 16 + n16;
      f32x4 vs = f[t];
#pragma unroll
      for (int r = 0; r < 4; ++r) vs[r] = fmaxf(vs[r] + b_self[co + r], 0.f);
      *(f32x4*)(sXS + p * XROW + co) = vs;
    }
  }
  __syncthreads();

  // ---- combine: pred = xs + sum_j relu(m_j*(cA[o1_j]+cB[o2_j]) + br)
  // 4 passes x 4 floats/thread; 30 gather loads in flight per pass.
  {
    const size_t bb = (size_t)b * 16 * IMGSZ;
#pragma unroll 1
    for (int pass = 0; pass < 4; ++pass) {
      const int e = tid * 4 + pass * 1024;   // 4 consecutive [px][ic] floats
      const int e_px = e >> 6, e_ic = e & 63;
      f32x4 v1[15], v2[15];
#pragma unroll
      for (int j = 0; j < 15; ++j) {
        v1[j] = *(const f32x4*)(cA + bb + (size_t)so1[j] * IMGSZ + e);
        v2[j] = *(const f32x4*)(cB + bb + (size_t)so2[j] * IMGSZ + e);
      }
      f32x4 xv = *(const f32x4*)(sXS + e_px * XROW + e_ic);
      float acc[4], br[4];
#pragma unroll
      for (int r = 0; r < 4; ++r) { br[r] = b_rel[e_ic + r]; acc[r] = xv[r]; }
#pragma unroll
      for (int j = 0; j < 15; ++j) {
        float m = sm[j];
#pragma unroll
        for (int r = 0; r < 4; ++r)
          acc[r] += fmaxf(m * (v1[j][r] + v2[j][r]) + br[r], 0.f);
      }
      uint2 pk;
      pk.x = (unsigned)f2bf(acc[0]) | ((unsigned)f2bf(acc[1]) << 16);
      pk.y = (unsigned)f2bf(acc[2]) | ((unsigned)f2bf(acc[3]) << 16);
      *(uint2*)(sPred + e_px * ROW + e_ic) = pk;
    }
  }
  __syncthreads();

  // ---- aff conv: sPred -> a -> sX cols 0..63
  {
    f32x4 f[4] = {};
    const unsigned short* WA = Wt + 36864 + aw64;
#pragma unroll
    for (int tap = 0; tap < 9; ++tap) {
      const int dy = tap / 3 - 1, dx = tap % 3 - 1;
      int spt[4];
#pragma unroll
      for (int t = 0; t < 4; ++t) {
        int sy = pyt[t] + dy, sx = pxt[t] + dx;
        spt[t] = ((unsigned)sy < 8u && (unsigned)sx < 8u) ? (sy * 8 + sx) : 64;
      }
#pragma unroll
      for (int ks = 0; ks < 2; ++ks) {
        bf16x8 a = *(const bf16x8*)(WA + tap * 4096 + ks * 32);
#pragma unroll
        for (int t = 0; t < 4; ++t) {
          bf16x8 bt = *(const bf16x8*)(sPred + spt[t] * ROW + ks * 32 + q * 8);
          f[t] = __builtin_amdgcn_mfma_f32_16x16x32_bf16(a, bt, f[t], 0, 0, 0);
        }
      }
    }
#pragma unroll
    for (int t = 0; t < 4; ++t) {
      int p = t * 16 + n16;
      float v0 = fmaxf(f[t][0] + b_aff[co + 0], 0.f);
      float v1 = fmaxf(f[t][1] + b_aff[co + 1], 0.f);
      float v2 = fmaxf(f[t][2] + b_aff[co + 2], 0.f);
      float v3 = fmaxf(f[t][3] + b_aff[co + 3], 0.f);
      uint2 pk;
      pk.x = (unsigned)f2bf(v0) | ((unsigned)f2bf(v1) << 16);
      pk.y = (unsigned)f2bf(v2) | ((unsigned)f2bf(v3) << 16);
      *(uint2*)(sX + p * ROW2 + co) = pk;
    }
  }
  __syncthreads();

  // ---- agg conv: sX (128 ic: [a|x]) -> out fp32 [ic][px]
  {
    f32x4 g[4] = {};
    const unsigned short* WG = Wt + 147456 + aw128;
#pragma unroll
    for (int tap = 0; tap < 9; ++tap) {
      const int dy = tap / 3 - 1, dx = tap % 3 - 1;
      int spt[4];
#pragma unroll
      for (int t = 0; t < 4; ++t) {
        int sy = pyt[t] + dy, sx = pxt[t] + dx;
        spt[t] = ((unsigned)sy < 8u && (unsigned)sx < 8u) ? (sy * 8 + sx) : 64;
      }
#pragma unroll
      for (int ks = 0; ks < 4; ++ks) {
        bf16x8 a = *(const bf16x8*)(WG + tap * 8192 + ks * 32);
#pragma unroll
        for (int t = 0; t < 4; ++t) {
          bf16x8 bt = *(const bf16x8*)(sX + spt[t] * ROW2 + ks * 32 + q * 8);
          g[t] = __builtin_amdgcn_mfma_f32_16x16x32_bf16(a, bt, g[t], 0, 0, 0);
        }
      }
    }
    float* ob = out + (size_t)img * IMGSZ;
#pragma unroll
    for (int t = 0; t < 4; ++t) {
      int p = t * 16 + n16;
#pragma unroll
      for (int r = 0; r < 4; ++r)
        ob[(co + r) * 64 + p] = fmaxf(g[t][r] + b_agg[co + r], 0.f);
    }
  }
}

extern "C" void kernel_launch(void* const* d_in, const int* in_sizes, int n_in,
                              void* d_out, int out_size, void* d_ws, size_t ws_size,
                              hipStream_t stream) {
  const float* x      = (const float*)d_in[0];
  const int*   g_idx  = (const int*)  d_in[1];
  const float* W_rel  = (const float*)d_in[2];
  const float* b_rel  = (const float*)d_in[3];
  const float* W_self = (const float*)d_in[4];
  const float* b_self = (const float*)d_in[5];
  const float* W_aff  = (const float*)d_in[6];
  const float* b_aff  = (const float*)d_in[7];
  const float* W_agg  = (const float*)d_in[8];
  const float* b_agg  = (const float*)d_in[9];
  float* out = (float*)d_out;

  float* ws = (float*)d_ws;
  float* cA = ws;                                            // [512][64][64] fp32
  float* cB = ws + 2097152;
  unsigned short* Wt = (unsigned short*)(ws + 2 * 2097152);  // 221184 bf16

  prep_w<<<864, 256, 0, stream>>>(W_rel, W_self, W_aff, W_agg, Wt);
  k1<<<NIMG, 256, 0, stream>>>(x, Wt, cA, cB);
  k2<<<NIMG, 256, 0, stream>>>(x, g_idx, Wt, b_rel, b_self, b_aff, b_agg,
                               cA, cB, out);
}

// Round 15
// 116.995 us; speedup vs baseline: 1.3593x; 1.0477x over previous
//
#include <hip/hip_runtime.h>

// InterNet B=32,N=16,D=64,P=8. Factorized: conv(mask*[y1;y2],W_rel) =
// mask*(convA(x[o1]) + convB(x[o2])). 3 dispatches, no inter-block sync.
//   prep_w: weights -> bf16 Wt [tap][oc][ic]  (tiny)
//   k1: per image: stage x fp32 -> LDS bf16; relA/relB convs -> cA/cB  *bf16*
//   k2: per image: stage x -> LDS; self conv -> xs (LDS, fp32);
//       burst combine (15 static pairs, 30 uint2 loads in flight/pass) ->
//       pred(LDS) -> aff conv -> a(LDS[a|x]) -> agg conv(128ic) -> out
// vs R14: cA/cB stored bf16 -- halves k1 writes and combine L2 traffic; burst
// fits in 60 VGPRs so all 30 loads stay in flight. Only new rounding: cA/cB.

#define NIMG 512
#define IMGSZ 4096

using bf16x8 = __attribute__((ext_vector_type(8))) short;
using f32x4  = __attribute__((ext_vector_type(4))) float;
using u16x8  = __attribute__((ext_vector_type(8))) unsigned short;

__device__ inline unsigned short f2bf(float f) {
  union { float f; unsigned u; } v; v.f = f;
  unsigned r = v.u + 0x7fffu + ((v.u >> 16) & 1u);
  return (unsigned short)(r >> 16);
}

__device__ inline f32x4 bf4_to_f32(uint2 p) {
  union { unsigned u; float f; } c;
  f32x4 r;
  c.u = (p.x & 0xffffu) << 16;  r[0] = c.f;
  c.u = (p.x & 0xffff0000u);    r[1] = c.f;
  c.u = (p.y & 0xffffu) << 16;  r[2] = c.f;
  c.u = (p.y & 0xffff0000u);    r[3] = c.f;
  return r;
}

// Wt slots: self [9][64][64] @0, aff @36864, rel [9][64][128] @73728,
//           agg [9][64][128] @147456.
__global__ __launch_bounds__(256) void prep_w(
    const float* __restrict__ Wr, const float* __restrict__ Ws,
    const float* __restrict__ Wa, const float* __restrict__ Wg,
    unsigned short* __restrict__ Wt)
{
  int idx = blockIdx.x * 256 + threadIdx.x;
  if (idx >= 221184) return;
  float v;
  if (idx < 73728) {
    int c = idx / 36864, r = idx % 36864;
    int t = r >> 12, oc = (r >> 6) & 63, ic = r & 63;
    v = (c == 0 ? Ws : Wa)[oc * 576 + ic * 9 + t];
  } else {
    int r2 = idx - 73728;
    int half = r2 / 73728, rr = r2 % 73728;
    int t = rr >> 13, oc = (rr >> 7) & 63, ic = rr & 127;
    v = (half ? Wg : Wr)[oc * 1152 + ic * 9 + t];
  }
  Wt[idx] = f2bf(v);
}

// batch b pinned to XCD b&7 (perf heuristic; correctness never depends on it)
__device__ inline void decode_img(int j, int& b, int& o) {
  b = ((j >> 7) << 3) | (j & 7);
  o = (j >> 3) & 15;
}

// stage x (fp32 [ic][px]) -> LDS bf16 [px][stride ROWX], cols at +coff.
template<int ROWX>
__device__ inline void stage_x(const float* __restrict__ xb,
                               unsigned short* __restrict__ s,
                               int coff, int w, int px) {
#pragma unroll
  for (int r = 0; r < 8; ++r) {
    int ic0 = (w + 4 * r) * 2;
    const float* sp = xb + ic0 * 64;
    float a = sp[px], c = sp[64 + px];
    *(unsigned*)(s + px * ROWX + coff + ic0) =
        (unsigned)f2bf(a) | ((unsigned)f2bf(c) << 16);
  }
}

__global__ __launch_bounds__(256) void k1(
    const float* __restrict__ x,
    const unsigned short* __restrict__ Wt,
    unsigned short* __restrict__ cA, unsigned short* __restrict__ cB)
{
  constexpr int ROW = 72;
  __shared__ __align__(16) unsigned short sX[65 * ROW];
  int b, o;
  decode_img(blockIdx.x, b, o);
  const int img = b * 16 + o;
  const int tid = threadIdx.x;
  const int w = tid >> 6, lane = tid & 63;

  stage_x<ROW>(x + (size_t)img * IMGSZ, sX, 0, w, lane);
  if (tid < 36) ((unsigned*)(sX + 64 * ROW))[tid] = 0;
  __syncthreads();

  const int q = lane >> 4, n16 = lane & 15;
  const int ocb = w * 16;
  const int co = ocb + q * 4;

  int pyt[4], pxt[4];
#pragma unroll
  for (int t = 0; t < 4; ++t) { int p = t * 16 + n16; pyt[t] = p >> 3; pxt[t] = p & 7; }

  f32x4 aA[4] = {}, aB[4] = {};
  const unsigned short* WA = Wt + 73728 + (ocb + n16) * 128 + q * 8;  // rel ic 0..63
  const unsigned short* WB = WA + 64;                                 // rel ic 64..127
#pragma unroll
  for (int tap = 0; tap < 9; ++tap) {
    const int dy = tap / 3 - 1, dx = tap % 3 - 1;
    int spt[4];
#pragma unroll
    for (int t = 0; t < 4; ++t) {
      int sy = pyt[t] + dy, sx = pxt[t] + dx;
      spt[t] = ((unsigned)sy < 8u && (unsigned)sx < 8u) ? (sy * 8 + sx) : 64;
    }
#pragma unroll
    for (int ks = 0; ks < 2; ++ks) {
      bf16x8 aa = *(const bf16x8*)(WA + tap * 8192 + ks * 32);
      bf16x8 ab = *(const bf16x8*)(WB + tap * 8192 + ks * 32);
#pragma unroll
      for (int t = 0; t < 4; ++t) {
        bf16x8 bt = *(const bf16x8*)(sX + spt[t] * ROW + ks * 32 + q * 8);
        aA[t] = __builtin_amdgcn_mfma_f32_16x16x32_bf16(aa, bt, aA[t], 0, 0, 0);
        aB[t] = __builtin_amdgcn_mfma_f32_16x16x32_bf16(ab, bt, aB[t], 0, 0, 0);
      }
    }
  }

  const size_t ib = (size_t)img * IMGSZ;
#pragma unroll
  for (int t = 0; t < 4; ++t) {
    int p = t * 16 + n16;
    uint2 pa, pb;
    pa.x = (unsigned)f2bf(aA[t][0]) | ((unsigned)f2bf(aA[t][1]) << 16);
    pa.y = (unsigned)f2bf(aA[t][2]) | ((unsigned)f2bf(aA[t][3]) << 16);
    pb.x = (unsigned)f2bf(aB[t][0]) | ((unsigned)f2bf(aB[t][1]) << 16);
    pb.y = (unsigned)f2bf(aB[t][2]) | ((unsigned)f2bf(aB[t][3]) << 16);
    *(uint2*)(cA + ib + p * 64 + co) = pa;
    *(uint2*)(cB + ib + p * 64 + co) = pb;
  }
}

__global__ __launch_bounds__(256, 2) void k2(
    const float* __restrict__ x,
    const int* __restrict__ g_idx,
    const unsigned short* __restrict__ Wt,
    const float* __restrict__ b_rel, const float* __restrict__ b_self,
    const float* __restrict__ b_aff, const float* __restrict__ b_agg,
    const unsigned short* __restrict__ cA, const unsigned short* __restrict__ cB,
    float* __restrict__ out)
{
  constexpr int ROW = 72, ROW2 = 136, XROW = 68;
  __shared__ __align__(16) unsigned short sX[65 * ROW2];   // [a | x] bf16
  __shared__ __align__(16) unsigned short sPred[65 * ROW]; // pred bf16
  __shared__ __align__(16) float sXS[64 * XROW];           // xs fp32
  __shared__ int so1[15], so2[15];
  __shared__ float sm[15];

  int b, i;
  decode_img(blockIdx.x, b, i);
  const int img = b * 16 + i;
  const int tid = threadIdx.x;
  const int w = tid >> 6, lane = tid & 63;

  if (tid < 15) {
    const int* gp = g_idx + ((size_t)b * 240 + i * 15 + tid) * 3;
    so1[tid] = gp[0] & 15;   // tile(x, n-1): x1[j] = x[j % 16]
    so2[tid] = gp[1] & 15;
    sm[tid]  = (float)gp[2];
  }

  stage_x<ROW2>(x + (size_t)img * IMGSZ, sX, 64, w, lane);
  if (tid < 68) ((unsigned*)(sX + 64 * ROW2))[tid] = 0;
  if (tid < 36) ((unsigned*)(sPred + 64 * ROW))[tid] = 0;
  __syncthreads();

  const int q = lane >> 4, n16 = lane & 15;
  const int ocb = w * 16;
  const int co = ocb + q * 4;
  const int aw64  = (ocb + n16) * 64 + q * 8;
  const int aw128 = (ocb + n16) * 128 + q * 8;

  int pyt[4], pxt[4];
#pragma unroll
  for (int t = 0; t < 4; ++t) { int p = t * 16 + n16; pyt[t] = p >> 3; pxt[t] = p & 7; }

  // ---- self conv (from staged x) -> xs in LDS fp32
  {
    f32x4 f[4] = {};
    const unsigned short* WS = Wt + aw64;
#pragma unroll
    for (int tap = 0; tap < 9; ++tap) {
      const int dy = tap / 3 - 1, dx = tap % 3 - 1;
      int spt[4];
#pragma unroll
      for (int t = 0; t < 4; ++t) {
        int sy = pyt[t] + dy, sx = pxt[t] + dx;
        spt[t] = ((unsigned)sy < 8u && (unsigned)sx < 8u) ? (sy * 8 + sx) : 64;
      }
#pragma unroll
      for (int ks = 0; ks < 2; ++ks) {
        bf16x8 a = *(const bf16x8*)(WS + tap * 4096 + ks * 32);
#pragma unroll
        for (int t = 0; t < 4; ++t) {
          bf16x8 bt = *(const bf16x8*)(sX + spt[t] * ROW2 + 64 + ks * 32 + q * 8);
          f[t] = __builtin_amdgcn_mfma_f32_16x16x32_bf16(a, bt, f[t], 0, 0, 0);
        }
      }
    }
#pragma unroll
    for (int t = 0; t < 4; ++t) {
      int p = t * 16 + n16;
      f32x4 vs = f[t];
#pragma unroll
      for (int r = 0; r < 4; ++r) vs[r] = fmaxf(vs[r] + b_self[co + r], 0.f);
      *(f32x4*)(sXS + p * XROW + co) = vs;
    }
  }
  __syncthreads();

  // ---- combine: pred = xs + sum_j relu(m_j*(cA[o1_j]+cB[o2_j]) + br)
  // 4 passes x 4 elems/thread; 30 uint2 (bf16x4) loads in flight per pass.
  {
    const size_t bb = (size_t)b * 16 * IMGSZ;
#pragma unroll 1
    for (int pass = 0; pass < 4; ++pass) {
      const int e = tid * 4 + pass * 1024;   // 4 consecutive [px][ic] elems
      const int e_px = e >> 6, e_ic = e & 63;
      uint2 v1[15], v2[15];
#pragma unroll
      for (int j = 0; j < 15; ++j) {
        v1[j] = *(const uint2*)(cA + bb + (size_t)so1[j] * IMGSZ + e);
        v2[j] = *(const uint2*)(cB + bb + (size_t)so2[j] * IMGSZ + e);
      }
      f32x4 xv = *(const f32x4*)(sXS + e_px * XROW + e_ic);
      float acc[4], br[4];
#pragma unroll
      for (int r = 0; r < 4; ++r) { br[r] = b_rel[e_ic + r]; acc[r] = xv[r]; }
#pragma unroll
      for (int j = 0; j < 15; ++j) {
        float m = sm[j];
        f32x4 a1 = bf4_to_f32(v1[j]);
        f32x4 a2 = bf4_to_f32(v2[j]);
#pragma unroll
        for (int r = 0; r < 4; ++r)
          acc[r] += fmaxf(m * (a1[r] + a2[r]) + br[r], 0.f);
      }
      uint2 pk;
      pk.x = (unsigned)f2bf(acc[0]) | ((unsigned)f2bf(acc[1]) << 16);
      pk.y = (unsigned)f2bf(acc[2]) | ((unsigned)f2bf(acc[3]) << 16);
      *(uint2*)(sPred + e_px * ROW + e_ic) = pk;
    }
  }
  __syncthreads();

  // ---- aff conv: sPred -> a -> sX cols 0..63
  {
    f32x4 f[4] = {};
    const unsigned short* WA = Wt + 36864 + aw64;
#pragma unroll
    for (int tap = 0; tap < 9; ++tap) {
      const int dy = tap / 3 - 1, dx = tap % 3 - 1;
      int spt[4];
#pragma unroll
      for (int t = 0; t < 4; ++t) {
        int sy = pyt[t] + dy, sx = pxt[t] + dx;
        spt[t] = ((unsigned)sy < 8u && (unsigned)sx < 8u) ? (sy * 8 + sx) : 64;
      }
#pragma unroll
      for (int ks = 0; ks < 2; ++ks) {
        bf16x8 a = *(const bf16x8*)(WA + tap * 4096 + ks * 32);
#pragma unroll
        for (int t = 0; t < 4; ++t) {
          bf16x8 bt = *(const bf16x8*)(sPred + spt[t] * ROW + ks * 32 + q * 8);
          f[t] = __builtin_amdgcn_mfma_f32_16x16x32_bf16(a, bt, f[t], 0, 0, 0);
        }
      }
    }
#pragma unroll
    for (int t = 0; t < 4; ++t) {
      int p = t * 16 + n16;
      float v0 = fmaxf(f[t][0] + b_aff[co + 0], 0.f);
      float v1 = fmaxf(f[t][1] + b_aff[co + 1], 0.f);
      float v2 = fmaxf(f[t][2] + b_aff[co + 2], 0.f);
      float v3 = fmaxf(f[t][3] + b_aff[co + 3], 0.f);
      uint2 pk;
      pk.x = (unsigned)f2bf(v0) | ((unsigned)f2bf(v1) << 16);
      pk.y = (unsigned)f2bf(v2) | ((unsigned)f2bf(v3) << 16);
      *(uint2*)(sX + p * ROW2 + co) = pk;
    }
  }
  __syncthreads();

  // ---- agg conv: sX (128 ic: [a|x]) -> out fp32 [ic][px]
  {
    f32x4 g[4] = {};
    const unsigned short* WG = Wt + 147456 + aw128;
#pragma unroll
    for (int tap = 0; tap < 9; ++tap) {
      const int dy = tap / 3 - 1, dx = tap % 3 - 1;
      int spt[4];
#pragma unroll
      for (int t = 0; t < 4; ++t) {
        int sy = pyt[t] + dy, sx = pxt[t] + dx;
        spt[t] = ((unsigned)sy < 8u && (unsigned)sx < 8u) ? (sy * 8 + sx) : 64;
      }
#pragma unroll
      for (int ks = 0; ks < 4; ++ks) {
        bf16x8 a = *(const bf16x8*)(WG + tap * 8192 + ks * 32);
#pragma unroll
        for (int t = 0; t < 4; ++t) {
          bf16x8 bt = *(const bf16x8*)(sX + spt[t] * ROW2 + ks * 32 + q * 8);
          g[t] = __builtin_amdgcn_mfma_f32_16x16x32_bf16(a, bt, g[t], 0, 0, 0);
        }
      }
    }
    float* ob = out + (size_t)img * IMGSZ;
#pragma unroll
    for (int t = 0; t < 4; ++t) {
      int p = t * 16 + n16;
#pragma unroll
      for (int r = 0; r < 4; ++r)
        ob[(co + r) * 64 + p] = fmaxf(g[t][r] + b_agg[co + r], 0.f);
    }
  }
}

extern "C" void kernel_launch(void* const* d_in, const int* in_sizes, int n_in,
                              void* d_out, int out_size, void* d_ws, size_t ws_size,
                              hipStream_t stream) {
  const float* x      = (const float*)d_in[0];
  const int*   g_idx  = (const int*)  d_in[1];
  const float* W_rel  = (const float*)d_in[2];
  const float* b_rel  = (const float*)d_in[3];
  const float* W_self = (const float*)d_in[4];
  const float* b_self = (const float*)d_in[5];
  const float* W_aff  = (const float*)d_in[6];
  const float* b_aff  = (const float*)d_in[7];
  const float* W_agg  = (const float*)d_in[8];
  const float* b_agg  = (const float*)d_in[9];
  float* out = (float*)d_out;

  unsigned short* cA = (unsigned short*)d_ws;      // [512][64][64] bf16
  unsigned short* cB = cA + 2097152;
  unsigned short* Wt = cB + 2097152;               // 221184 bf16

  prep_w<<<864, 256, 0, stream>>>(W_rel, W_self, W_aff, W_agg, Wt);
  k1<<<NIMG, 256, 0, stream>>>(x, Wt, cA, cB);
  k2<<<NIMG, 256, 0, stream>>>(x, g_idx, Wt, b_rel, b_self, b_aff, b_agg,
                               cA, cB, out);
}